// Round 1
// baseline (480.951 us; speedup 1.0000x reference)
//
#include <hip/hip_runtime.h>
#include <hip/hip_bf16.h>
#include <stdint.h>

#define NUM_CLASSES 100000
#define C_PAD       100096   // 782 * 128
#define NROWS       1024
#define KDIM        512
#define BM          128
#define BN          128
#define BK          32       // bf16 elems per K-step (64 bytes per row)

#define L2E64 92.3324826f    // 64 * log2(e)

typedef __bf16 bf16x8 __attribute__((ext_vector_type(8)));
typedef float  f32x4  __attribute__((ext_vector_type(4)));
typedef unsigned short u16x8 __attribute__((ext_vector_type(8)));

__device__ __forceinline__ unsigned short f2bf(float x) {
    unsigned int u = __float_as_uint(x);
    u = u + 0x7fffu + ((u >> 16) & 1u);   // RNE
    return (unsigned short)(u >> 16);
}
__device__ __forceinline__ float bf2f(unsigned short x) {
    return __uint_as_float(((unsigned int)x) << 16);
}
// exp(64*c - 64) via native exp2 — MUST be identical in gemm and finalize
__device__ __forceinline__ float fexp64(float c) {
    return exp2f(fmaf(c, L2E64, -L2E64));
}
__device__ __forceinline__ void gload_lds16(const void* g, void* l) {
    __builtin_amdgcn_global_load_lds(
        (const __attribute__((address_space(1))) unsigned int*)g,
        (__attribute__((address_space(3))) unsigned int*)l,
        16, 0, 0);
}

// ---- normalize rows of [rows_total x 512] f32 -> bf16 (zero-fill pad rows) ----
__global__ void norm_rows_bf16(const float* __restrict__ in,
                               unsigned short* __restrict__ out,
                               int rows_valid, int rows_total) {
    const int lane = threadIdx.x & 63;
    const int row  = blockIdx.x * 4 + (threadIdx.x >> 6);
    if (row >= rows_total) return;
    unsigned short* dst = out + (size_t)row * KDIM + lane * 8;
    if (row >= rows_valid) {
        u16x8 z;
        #pragma unroll
        for (int i = 0; i < 8; ++i) z[i] = 0;
        *(u16x8*)dst = z;
        return;
    }
    const float4* p = (const float4*)(in + (size_t)row * KDIM + lane * 8);
    float4 a = p[0], b = p[1];
    float ss = a.x*a.x + a.y*a.y + a.z*a.z + a.w*a.w
             + b.x*b.x + b.y*b.y + b.z*b.z + b.w*b.w;
    #pragma unroll
    for (int m = 1; m < 64; m <<= 1) ss += __shfl_xor(ss, m, 64);
    float scale = 1.0f / fmaxf(sqrtf(ss), 1e-12f);
    float v[8] = {a.x, a.y, a.z, a.w, b.x, b.y, b.z, b.w};
    u16x8 o;
    #pragma unroll
    for (int i = 0; i < 8; ++i) o[i] = f2bf(v[i] * scale);
    *(u16x8*)dst = o;
}

// ---- main GEMM: cos = f_n . w_c, fused exp-sum epilogue ----
__global__ __launch_bounds__(256) void arcface_gemm(
        const unsigned short* __restrict__ fb,   // [1024][512] bf16 (normalized)
        const unsigned short* __restrict__ wb,   // [C_PAD][512] bf16 (normalized)
        float* __restrict__ rowsum) {            // [1024] f32, pre-zeroed
    __shared__ __align__(16) unsigned short ldsA[BM * BK];  // 8 KB
    __shared__ __align__(16) unsigned short ldsB[BN * BK];  // 8 KB
    __shared__ float lds_rs[BM];

    const int tid  = threadIdx.x;
    const int lane = tid & 63;
    const int wid  = tid >> 6;
    const int wr   = wid >> 1;    // wave row (0..1), 64 rows each
    const int wc   = wid & 1;     // wave col (0..1), 64 cols each
    const int row0 = blockIdx.y * BM;
    const int col0 = blockIdx.x * BN;
    const int l15  = lane & 15;
    const int kg   = lane >> 4;

    f32x4 acc[4][4];
    #pragma unroll
    for (int m = 0; m < 4; ++m)
        #pragma unroll
        for (int n = 0; n < 4; ++n)
            #pragma unroll
            for (int j = 0; j < 4; ++j) acc[m][n][j] = 0.f;

    const char* fbB = (const char*)fb;
    const char* wbB = (const char*)wb;
    const int o0 = tid * 16;   // per-thread byte offset within 8 KB tile

    for (int kt = 0; kt < KDIM / BK; ++kt) {
        __syncthreads();
        const int kb = kt * (BK * 2);   // byte offset along K (64 B)
        #pragma unroll
        for (int c = 0; c < 2; ++c) {
            const int o  = o0 + c * 4096;
            const int r  = o >> 6;       // row within tile
            const int cb = o & 63;       // byte within row
            gload_lds16(fbB + (size_t)(row0 + r) * (KDIM * 2) + kb + cb,
                        (char*)ldsA + o);
            gload_lds16(wbB + (size_t)(col0 + r) * (KDIM * 2) + kb + cb,
                        (char*)ldsB + o);
        }
        __syncthreads();

        bf16x8 af[4], bfr[4];
        #pragma unroll
        for (int m = 0; m < 4; ++m) {
            const int rr = wr * 64 + m * 16 + l15;
            af[m] = *(const bf16x8*)((const char*)ldsA + rr * 64 + kg * 16);
        }
        #pragma unroll
        for (int n = 0; n < 4; ++n) {
            const int cr = wc * 64 + n * 16 + l15;
            bfr[n] = *(const bf16x8*)((const char*)ldsB + cr * 64 + kg * 16);
        }
        #pragma unroll
        for (int m = 0; m < 4; ++m)
            #pragma unroll
            for (int n = 0; n < 4; ++n)
                acc[m][n] = __builtin_amdgcn_mfma_f32_16x16x32_bf16(
                                af[m], bfr[n], acc[m][n], 0, 0, 0);
    }

    // epilogue: t = exp(64*clamp(cos)-64), row-sum over this block's columns
    if (tid < BM) lds_rs[tid] = 0.f;
    __syncthreads();

    float rs[4][4];
    #pragma unroll
    for (int m = 0; m < 4; ++m)
        #pragma unroll
        for (int j = 0; j < 4; ++j) rs[m][j] = 0.f;

    #pragma unroll
    for (int n = 0; n < 4; ++n) {
        const int colg = col0 + wc * 64 + n * 16 + l15;
        const bool valid = colg < NUM_CLASSES;
        #pragma unroll
        for (int m = 0; m < 4; ++m) {
            #pragma unroll
            for (int j = 0; j < 4; ++j) {
                float c = acc[m][n][j];
                c = fminf(fmaxf(c, -1.f), 1.f);
                float t = fexp64(c);
                rs[m][j] += valid ? t : 0.f;
            }
        }
    }
    #pragma unroll
    for (int m = 0; m < 4; ++m) {
        #pragma unroll
        for (int j = 0; j < 4; ++j) {
            float v = rs[m][j];
            v += __shfl_xor(v, 1, 64);
            v += __shfl_xor(v, 2, 64);
            v += __shfl_xor(v, 4, 64);
            v += __shfl_xor(v, 8, 64);
            rs[m][j] = v;   // full row-sum over 64 cols, replicated in 16 lanes
        }
    }
    if (l15 == 0) {
        #pragma unroll
        for (int m = 0; m < 4; ++m)
            #pragma unroll
            for (int j = 0; j < 4; ++j)
                atomicAdd(&lds_rs[wr * 64 + m * 16 + kg * 4 + j], rs[m][j]);
    }
    __syncthreads();
    if (tid < BM) atomicAdd(&rowsum[row0 + tid], lds_rs[tid]);
}

// ---- label-column cosines: one wave per row ----
__global__ void label_dot(const unsigned short* __restrict__ fb,
                          const unsigned short* __restrict__ wb,
                          const int* __restrict__ labels,
                          float* __restrict__ coslab) {
    const int lane = threadIdx.x & 63;
    const int row  = blockIdx.x * 4 + (threadIdx.x >> 6);
    if (row >= NROWS) return;
    const int lab = labels[row];
    u16x8 a = *(const u16x8*)(fb + (size_t)row * KDIM + lane * 8);
    u16x8 b = *(const u16x8*)(wb + (size_t)lab * KDIM + lane * 8);
    float s = 0.f;
    #pragma unroll
    for (int i = 0; i < 8; ++i) s = fmaf(bf2f(a[i]), bf2f(b[i]), s);
    #pragma unroll
    for (int m = 1; m < 64; m <<= 1) s += __shfl_xor(s, m, 64);
    if (lane == 0) coslab[row] = s;
}

// ---- finalize: margin math + logsumexp + mean NLL ----
__global__ void finalize(const float* __restrict__ rowsum,
                         const float* __restrict__ coslab,
                         float* __restrict__ out) {
    const float COS_M   =  0.87758256189f;  // cos(0.5)
    const float SIN_M   =  0.47942553860f;  // sin(0.5)
    const float MIN_COS = -0.87758256189f;  // cos(pi - 0.5)
    __shared__ float red[256];
    const int tid = threadIdx.x;
    float acc = 0.f;
    for (int r = tid; r < NROWS; r += 256) {
        float c = fminf(fmaxf(coslab[r], -1.f), 1.f);
        float sn = sqrtf(1.f - c * c + 1e-5f);
        float cm = c * COS_M - sn * SIN_M;
        float target = (c > MIN_COS) ? cm : (c - sn * 0.5f);
        float adj = rowsum[r] - fexp64(c) + fexp64(target);
        acc += 64.f + logf(adj) - 64.f * target;
    }
    red[tid] = acc;
    __syncthreads();
    for (int s = 128; s > 0; s >>= 1) {
        if (tid < s) red[tid] += red[tid + s];
        __syncthreads();
    }
    if (tid == 0) out[0] = red[0] / (float)NROWS;
}

extern "C" void kernel_launch(void* const* d_in, const int* in_sizes, int n_in,
                              void* d_out, int out_size, void* d_ws, size_t ws_size,
                              hipStream_t stream) {
    const float* feats  = (const float*)d_in[0];   // [8,128,512]
    const float* w      = (const float*)d_in[1];   // [100000,512]
    const int*   labels = (const int*)d_in[2];     // [1024]
    float* out = (float*)d_out;

    char* ws = (char*)d_ws;
    unsigned short* wb = (unsigned short*)ws;                               // C_PAD*512 bf16
    unsigned short* fb = (unsigned short*)(ws + (size_t)C_PAD * KDIM * 2);  // 1024*512 bf16
    float* rowsum = (float*)(ws + (size_t)C_PAD * KDIM * 2
                                + (size_t)NROWS * KDIM * 2);                // [1024]
    float* coslab = rowsum + NROWS;                                         // [1024]

    hipMemsetAsync(rowsum, 0, NROWS * sizeof(float), stream);
    norm_rows_bf16<<<C_PAD / 4, 256, 0, stream>>>(w, wb, NUM_CLASSES, C_PAD);
    norm_rows_bf16<<<NROWS / 4, 256, 0, stream>>>(feats, fb, NROWS, NROWS);
    dim3 grid(C_PAD / BN, NROWS / BM);
    arcface_gemm<<<grid, 256, 0, stream>>>(fb, wb, rowsum);
    label_dot<<<NROWS / 4, 256, 0, stream>>>(fb, wb, labels, coslab);
    finalize<<<1, 256, 0, stream>>>(rowsum, coslab, out);
}

// Round 3
// 475.733 us; speedup vs baseline: 1.0110x; 1.0110x over previous
//
#include <hip/hip_runtime.h>
#include <hip/hip_bf16.h>
#include <stdint.h>

#define NUM_CLASSES 100000
#define C_PAD       100096   // 782 * 128
#define NROWS       1024
#define KDIM        512
#define BM          128
#define BN          128
#define BK          32       // bf16 elems per K-step
#define NKT         (KDIM / BK)          // 16 K-tiles
#define TILE_BYTES  8192                 // 128 rows * 64 B
#define RB_BYTES    (NKT * TILE_BYTES)   // 131072 B per 128-row block
#define RB_U16      (RB_BYTES / 2)       // 65536

#define L2E64 92.3324826f    // 64 * log2(e)

typedef __bf16 bf16x8 __attribute__((ext_vector_type(8)));
typedef float  f32x4  __attribute__((ext_vector_type(4)));
typedef unsigned short u16x8 __attribute__((ext_vector_type(8)));

__device__ __forceinline__ unsigned short f2bf(float x) {
    unsigned int u = __float_as_uint(x);
    u = u + 0x7fffu + ((u >> 16) & 1u);   // RNE
    return (unsigned short)(u >> 16);
}
__device__ __forceinline__ float bf2f(unsigned short x) {
    return __uint_as_float(((unsigned int)x) << 16);
}
// exp(64*c - 64) via native exp2 — identical in gemm and finalize
__device__ __forceinline__ float fexp64(float c) {
    return exp2f(fmaf(c, L2E64, -L2E64));
}
__device__ __forceinline__ void gload_lds16(const void* g, void* l) {
    __builtin_amdgcn_global_load_lds(
        (const __attribute__((address_space(1))) unsigned int*)g,
        (__attribute__((address_space(3))) unsigned int*)l,
        16, 0, 0);
}

// Tiled workspace layout: row r, K-chunk (kt,kg) [8 bf16 = 16 B] lives at
//   u16 offset: (r>>7)*RB_U16 + kt*4096 + kg*1024 + (r&127)*8
// i.e. each (row_blk, kt) tile is a contiguous 8 KB block laid out [kg][row][16B].
// GEMM staging is a linear 8 KB copy; fragment ds_reads are conflict-free.

// ---- normalize rows of [rows_total x 512] f32 -> bf16 tiled (zero-fill pad) ----
__global__ void norm_rows_tiled(const float* __restrict__ in,
                                unsigned short* __restrict__ out,
                                int rows_valid, int rows_total) {
    const int lane = threadIdx.x & 63;
    const int row  = blockIdx.x * 4 + (threadIdx.x >> 6);
    if (row >= rows_total) return;
    // lane holds K elems [8*lane, 8*lane+8) => kt = lane>>2, kg = lane&3
    unsigned short* dst = out + (size_t)(row >> 7) * RB_U16
                              + (lane >> 2) * 4096 + (lane & 3) * 1024
                              + (row & 127) * 8;
    if (row >= rows_valid) {
        u16x8 z;
        #pragma unroll
        for (int i = 0; i < 8; ++i) z[i] = 0;
        *(u16x8*)dst = z;
        return;
    }
    const float4* p = (const float4*)(in + (size_t)row * KDIM + lane * 8);
    float4 a = p[0], b = p[1];
    float ss = a.x*a.x + a.y*a.y + a.z*a.z + a.w*a.w
             + b.x*b.x + b.y*b.y + b.z*b.z + b.w*b.w;
    #pragma unroll
    for (int m = 1; m < 64; m <<= 1) ss += __shfl_xor(ss, m, 64);
    float scale = 1.0f / fmaxf(sqrtf(ss), 1e-12f);
    float v[8] = {a.x, a.y, a.z, a.w, b.x, b.y, b.z, b.w};
    u16x8 o;
    #pragma unroll
    for (int i = 0; i < 8; ++i) o[i] = f2bf(v[i] * scale);
    *(u16x8*)dst = o;
}

// ---- main GEMM: cos = f_n . w_c, fused exp-sum epilogue ----
__global__ __launch_bounds__(256) void arcface_gemm(
        const unsigned short* __restrict__ fbT,  // tiled [8 RB][16 kt][4 kg][128][8]
        const unsigned short* __restrict__ wbT,  // tiled [782 RB][...]
        float* __restrict__ rowsum) {            // [1024] f32, pre-zeroed
    __shared__ __align__(16) unsigned short ldsA[BM * BK];  // 8 KB, [kg][row][8]
    __shared__ __align__(16) unsigned short ldsB[BN * BK];  // 8 KB
    __shared__ float lds_rs[BM];

    const int tid  = threadIdx.x;
    const int lane = tid & 63;
    const int wid  = tid >> 6;
    const int wr   = wid >> 1;    // wave row (0..1), 64 rows each
    const int wc   = wid & 1;     // wave col (0..1), 64 cols each
    const int l15  = lane & 15;
    const int kg   = lane >> 4;

    // 1-D grid, 6256 = 8 XCDs * 782 blocks. Chunked XCD swizzle, then
    // M-fastest decode so the 8 M-blocks of one B-strip are consecutive
    // on the SAME XCD -> B strip read once into that XCD's L2.
    const int wgid = (blockIdx.x & 7) * 782 + (blockIdx.x >> 3);
    const int colb = wgid >> 3;   // 0..781
    const int mrow = wgid & 7;    // 0..7
    const int row0 = mrow * BM;
    const int col0 = colb * BN;

    const char* aBase = (const char*)fbT + (size_t)mrow * RB_BYTES;
    const char* bBase = (const char*)wbT + (size_t)colb * RB_BYTES;

    f32x4 acc[4][4];
    #pragma unroll
    for (int m = 0; m < 4; ++m)
        #pragma unroll
        for (int n = 0; n < 4; ++n)
            #pragma unroll
            for (int j = 0; j < 4; ++j) acc[m][n][j] = 0.f;

    const int o0 = tid * 16;

    for (int kt = 0; kt < NKT; ++kt) {
        __syncthreads();
        const char* aT = aBase + kt * TILE_BYTES;
        const char* bT = bBase + kt * TILE_BYTES;
        #pragma unroll
        for (int c = 0; c < 2; ++c) {
            const int o = o0 + c * 4096;
            gload_lds16(aT + o, (char*)ldsA + o);
            gload_lds16(bT + o, (char*)ldsB + o);
        }
        __syncthreads();

        bf16x8 af[4], bfr[4];
        #pragma unroll
        for (int m = 0; m < 4; ++m) {
            const int rr = wr * 64 + m * 16 + l15;
            af[m] = *(const bf16x8*)((const char*)ldsA + kg * 2048 + rr * 16);
        }
        #pragma unroll
        for (int n = 0; n < 4; ++n) {
            const int cr = wc * 64 + n * 16 + l15;
            bfr[n] = *(const bf16x8*)((const char*)ldsB + kg * 2048 + cr * 16);
        }
        #pragma unroll
        for (int m = 0; m < 4; ++m)
            #pragma unroll
            for (int n = 0; n < 4; ++n)
                acc[m][n] = __builtin_amdgcn_mfma_f32_16x16x32_bf16(
                                af[m], bfr[n], acc[m][n], 0, 0, 0);
    }

    // epilogue: t = exp(64*clamp(cos)-64), row-sum over this block's columns
    if (tid < BM) lds_rs[tid] = 0.f;
    __syncthreads();

    float rs[4][4];
    #pragma unroll
    for (int m = 0; m < 4; ++m)
        #pragma unroll
        for (int j = 0; j < 4; ++j) rs[m][j] = 0.f;

    #pragma unroll
    for (int n = 0; n < 4; ++n) {
        const int colg = col0 + wc * 64 + n * 16 + l15;
        const bool valid = colg < NUM_CLASSES;
        #pragma unroll
        for (int m = 0; m < 4; ++m) {
            #pragma unroll
            for (int j = 0; j < 4; ++j) {
                float c = acc[m][n][j];
                c = fminf(fmaxf(c, -1.f), 1.f);
                float t = fexp64(c);
                rs[m][j] += valid ? t : 0.f;
            }
        }
    }
    #pragma unroll
    for (int m = 0; m < 4; ++m) {
        #pragma unroll
        for (int j = 0; j < 4; ++j) {
            float v = rs[m][j];
            v += __shfl_xor(v, 1, 64);
            v += __shfl_xor(v, 2, 64);
            v += __shfl_xor(v, 4, 64);
            v += __shfl_xor(v, 8, 64);
            rs[m][j] = v;   // row-sum over this wave's 64 cols
        }
    }
    if (l15 == 0) {
        #pragma unroll
        for (int m = 0; m < 4; ++m)
            #pragma unroll
            for (int j = 0; j < 4; ++j)
                atomicAdd(&lds_rs[wr * 64 + m * 16 + kg * 4 + j], rs[m][j]);
    }
    __syncthreads();
    if (tid < BM) atomicAdd(&rowsum[row0 + tid], lds_rs[tid]);
}

// ---- label-column cosines: one wave per row (tiled workspace reads) ----
__global__ void label_dot(const unsigned short* __restrict__ fbT,
                          const unsigned short* __restrict__ wbT,
                          const int* __restrict__ labels,
                          float* __restrict__ coslab) {
    const int lane = threadIdx.x & 63;
    const int row  = blockIdx.x * 4 + (threadIdx.x >> 6);
    if (row >= NROWS) return;
    const int lab = labels[row];
    const size_t fo = (size_t)(row >> 7) * RB_U16 + (lane >> 2) * 4096
                    + (lane & 3) * 1024 + (row & 127) * 8;
    const size_t wo = (size_t)(lab >> 7) * RB_U16 + (lane >> 2) * 4096
                    + (lane & 3) * 1024 + (lab & 127) * 8;
    u16x8 a = *(const u16x8*)(fbT + fo);
    u16x8 b = *(const u16x8*)(wbT + wo);
    float s = 0.f;
    #pragma unroll
    for (int i = 0; i < 8; ++i) s = fmaf(bf2f(a[i]), bf2f(b[i]), s);
    #pragma unroll
    for (int m = 1; m < 64; m <<= 1) s += __shfl_xor(s, m, 64);
    if (lane == 0) coslab[row] = s;
}

// ---- finalize: margin math + logsumexp + mean NLL ----
__global__ void finalize(const float* __restrict__ rowsum,
                         const float* __restrict__ coslab,
                         float* __restrict__ out) {
    const float COS_M   =  0.87758256189f;  // cos(0.5)
    const float SIN_M   =  0.47942553860f;  // sin(0.5)
    const float MIN_COS = -0.87758256189f;  // cos(pi - 0.5)
    __shared__ float red[256];
    const int tid = threadIdx.x;
    float acc = 0.f;
    for (int r = tid; r < NROWS; r += 256) {
        float c = fminf(fmaxf(coslab[r], -1.f), 1.f);
        float sn = sqrtf(1.f - c * c + 1e-5f);
        float cm = c * COS_M - sn * SIN_M;
        float target = (c > MIN_COS) ? cm : (c - sn * 0.5f);
        float adj = rowsum[r] - fexp64(c) + fexp64(target);
        acc += 64.f + logf(adj) - 64.f * target;
    }
    red[tid] = acc;
    __syncthreads();
    for (int s = 128; s > 0; s >>= 1) {
        if (tid < s) red[tid] += red[tid + s];
        __syncthreads();
    }
    if (tid == 0) out[0] = red[0] / (float)NROWS;
}

extern "C" void kernel_launch(void* const* d_in, const int* in_sizes, int n_in,
                              void* d_out, int out_size, void* d_ws, size_t ws_size,
                              hipStream_t stream) {
    const float* feats  = (const float*)d_in[0];   // [8,128,512]
    const float* w      = (const float*)d_in[1];   // [100000,512]
    const int*   labels = (const int*)d_in[2];     // [1024]
    float* out = (float*)d_out;

    char* ws = (char*)d_ws;
    unsigned short* wbT = (unsigned short*)ws;                               // C_PAD*512 bf16 tiled
    unsigned short* fbT = (unsigned short*)(ws + (size_t)C_PAD * KDIM * 2);  // 1024*512 bf16 tiled
    float* rowsum = (float*)(ws + (size_t)C_PAD * KDIM * 2
                                + (size_t)NROWS * KDIM * 2);                 // [1024]
    float* coslab = rowsum + NROWS;                                          // [1024]

    hipMemsetAsync(rowsum, 0, NROWS * sizeof(float), stream);
    norm_rows_tiled<<<C_PAD / 4, 256, 0, stream>>>(w, wbT, NUM_CLASSES, C_PAD);
    norm_rows_tiled<<<NROWS / 4, 256, 0, stream>>>(feats, fbT, NROWS, NROWS);
    arcface_gemm<<<(C_PAD / BN) * (NROWS / BM), 256, 0, stream>>>(fbT, wbT, rowsum);
    label_dot<<<NROWS / 4, 256, 0, stream>>>(fbT, wbT, labels, coslab);
    finalize<<<1, 256, 0, stream>>>(rowsum, coslab, out);
}

// Round 4
// 465.382 us; speedup vs baseline: 1.0335x; 1.0222x over previous
//
#include <hip/hip_runtime.h>
#include <hip/hip_bf16.h>
#include <stdint.h>

#define NUM_CLASSES 100000
#define C_PAD       100096   // 782 * 128
#define NROWS       1024
#define KDIM        512
#define BM          128
#define BN          128
#define BK          32       // bf16 elems per K-step
#define NKT         (KDIM / BK)          // 16 K-tiles
#define TILE_BYTES  8192                 // 128 rows * 64 B
#define RB_BYTES    (NKT * TILE_BYTES)   // 131072 B per 128-row block
#define RB_U16      (RB_BYTES / 2)       // 65536

#define L2E64 92.3324826f    // 64 * log2(e)

typedef __bf16 bf16x8 __attribute__((ext_vector_type(8)));
typedef float  f32x4  __attribute__((ext_vector_type(4)));
typedef unsigned short u16x8 __attribute__((ext_vector_type(8)));

__device__ __forceinline__ unsigned short f2bf(float x) {
    unsigned int u = __float_as_uint(x);
    u = u + 0x7fffu + ((u >> 16) & 1u);   // RNE
    return (unsigned short)(u >> 16);
}
__device__ __forceinline__ float bf2f(unsigned short x) {
    return __uint_as_float(((unsigned int)x) << 16);
}
// exp(64*c - 64) via native exp2 — identical in gemm and finalize
__device__ __forceinline__ float fexp64(float c) {
    return exp2f(fmaf(c, L2E64, -L2E64));
}
__device__ __forceinline__ void gload_lds16(const void* g, void* l) {
    __builtin_amdgcn_global_load_lds(
        (const __attribute__((address_space(1))) unsigned int*)g,
        (__attribute__((address_space(3))) unsigned int*)l,
        16, 0, 0);
}

// Tiled workspace layout: row r, K-chunk (kt,kg) [8 bf16 = 16 B] lives at
//   u16 offset: (r>>7)*RB_U16 + kt*4096 + kg*1024 + (r&127)*8
// Each (row_blk, kt) tile is a contiguous 8 KB block laid out [kg][row][16B]:
// GEMM staging is a linear 8 KB copy; fragment ds_reads are conflict-free.

// ---- normalize rows of [rows_total x 512] f32 -> bf16 tiled, LDS-bounced
//      so global writes are 64B-per-4-lanes (ideal line count) ----
__global__ void norm_rows_tiled(const float* __restrict__ in,
                                unsigned short* __restrict__ out,
                                int rows_valid) {
    __shared__ __align__(16) unsigned short stg[4 * 64 * 8];  // 4 KB
    const int tid  = threadIdx.x;
    const int lane = tid & 63;
    const int wv   = tid >> 6;
    const int row  = blockIdx.x * 4 + wv;

    u16x8 o;
    #pragma unroll
    for (int i = 0; i < 8; ++i) o[i] = 0;
    if (row < rows_valid) {
        const float4* p = (const float4*)(in + (size_t)row * KDIM + lane * 8);
        float4 a = p[0], b = p[1];
        float ss = a.x*a.x + a.y*a.y + a.z*a.z + a.w*a.w
                 + b.x*b.x + b.y*b.y + b.z*b.z + b.w*b.w;
        #pragma unroll
        for (int m = 1; m < 64; m <<= 1) ss += __shfl_xor(ss, m, 64);
        float scale = 1.0f / fmaxf(sqrtf(ss), 1e-12f);
        float v[8] = {a.x, a.y, a.z, a.w, b.x, b.y, b.z, b.w};
        #pragma unroll
        for (int i = 0; i < 8; ++i) o[i] = f2bf(v[i] * scale);
    }
    // lane holds K-chunk (kt = lane>>2, kg = lane&3) of its row
    *(u16x8*)&stg[(wv * 64 + lane) * 8] = o;
    __syncthreads();

    // write phase: thread t -> chunk c = t>>2, row-in-4 = t&3.
    // Per wave-store: 16 segments of 64B (4 rows x 16B contiguous) = 16 lines.
    const int c    = tid >> 2;
    const int r4   = tid & 3;
    const int rowg = blockIdx.x * 4 + r4;
    u16x8 v = *(const u16x8*)&stg[(r4 * 64 + c) * 8];
    const size_t dst = (size_t)(rowg >> 7) * RB_U16
                     + (c >> 2) * 4096 + (c & 3) * 1024 + (rowg & 127) * 8;
    *(u16x8*)(out + dst) = v;
}

// ---- main GEMM: cos = f_n . w_c, fused exp-sum epilogue, 2-phase dbuf ----
__global__ __launch_bounds__(256) void arcface_gemm(
        const unsigned short* __restrict__ fbT,  // tiled [8 RB][16 kt][4 kg][128][8]
        const unsigned short* __restrict__ wbT,  // tiled [782 RB][...]
        float* __restrict__ rowsum) {            // [1024] f32, pre-zeroed
    __shared__ __align__(16) unsigned short ldsA[2][BM * BK];  // 2 x 8 KB
    __shared__ __align__(16) unsigned short ldsB[2][BN * BK];  // 2 x 8 KB
    __shared__ float lds_rs[BM];

    const int tid  = threadIdx.x;
    const int lane = tid & 63;
    const int wid  = tid >> 6;
    const int wr   = wid >> 1;    // wave row (0..1), 64 rows each
    const int wc   = wid & 1;     // wave col (0..1), 64 cols each
    const int l15  = lane & 15;
    const int kg   = lane >> 4;

    // 1-D grid, 6256 = 8 XCDs * 782. Chunked XCD swizzle + M-fastest decode:
    // the 8 M-blocks of one B-strip are consecutive on the SAME XCD.
    const int wgid = (blockIdx.x & 7) * 782 + (blockIdx.x >> 3);
    const int colb = wgid >> 3;   // 0..781
    const int mrow = wgid & 7;    // 0..7
    const int row0 = mrow * BM;

    const char* aBase = (const char*)fbT + (size_t)mrow * RB_BYTES;
    const char* bBase = (const char*)wbT + (size_t)colb * RB_BYTES;

    f32x4 acc[4][4];
    #pragma unroll
    for (int m = 0; m < 4; ++m)
        #pragma unroll
        for (int n = 0; n < 4; ++n)
            #pragma unroll
            for (int j = 0; j < 4; ++j) acc[m][n][j] = 0.f;

    const int o0 = tid * 16;

    // prologue: stage tile 0 into buffer 0
    #pragma unroll
    for (int ch = 0; ch < 2; ++ch) {
        const int o = o0 + ch * 4096;
        gload_lds16(aBase + o, (char*)ldsA[0] + o);
        gload_lds16(bBase + o, (char*)ldsB[0] + o);
    }
    __syncthreads();   // implicit vmcnt(0): tile 0 resident

    int cur = 0;
    for (int kt = 0; kt < NKT; ++kt) {
        // issue next tile's stage FIRST — flies during ds_read + MFMA below,
        // drained by the trailing __syncthreads()'s vmcnt(0).
        if (kt + 1 < NKT) {
            const char* aT = aBase + (kt + 1) * TILE_BYTES;
            const char* bT = bBase + (kt + 1) * TILE_BYTES;
            #pragma unroll
            for (int ch = 0; ch < 2; ++ch) {
                const int o = o0 + ch * 4096;
                gload_lds16(aT + o, (char*)ldsA[cur ^ 1] + o);
                gload_lds16(bT + o, (char*)ldsB[cur ^ 1] + o);
            }
        }

        bf16x8 af[4], bfr[4];
        #pragma unroll
        for (int m = 0; m < 4; ++m) {
            const int rr = wr * 64 + m * 16 + l15;
            af[m] = *(const bf16x8*)((const char*)ldsA[cur] + kg * 2048 + rr * 16);
        }
        #pragma unroll
        for (int n = 0; n < 4; ++n) {
            const int cr = wc * 64 + n * 16 + l15;
            bfr[n] = *(const bf16x8*)((const char*)ldsB[cur] + kg * 2048 + cr * 16);
        }
        #pragma unroll
        for (int m = 0; m < 4; ++m)
            #pragma unroll
            for (int n = 0; n < 4; ++n)
                acc[m][n] = __builtin_amdgcn_mfma_f32_16x16x32_bf16(
                                af[m], bfr[n], acc[m][n], 0, 0, 0);

        __syncthreads();   // one barrier per K-step: drains prefetch + guards reuse
        cur ^= 1;
    }

    // epilogue: t = exp(64*clamp(cos)-64), row-sum over this block's columns.
    // Pad columns (zero vectors) contribute exp(-64) each — negligible, no mask.
    if (tid < BM) lds_rs[tid] = 0.f;
    __syncthreads();

    float rs[4][4];
    #pragma unroll
    for (int m = 0; m < 4; ++m)
        #pragma unroll
        for (int j = 0; j < 4; ++j) rs[m][j] = 0.f;

    #pragma unroll
    for (int n = 0; n < 4; ++n) {
        #pragma unroll
        for (int m = 0; m < 4; ++m) {
            #pragma unroll
            for (int j = 0; j < 4; ++j) {
                float c = acc[m][n][j];
                c = fminf(fmaxf(c, -1.f), 1.f);
                rs[m][j] += fexp64(c);
            }
        }
    }
    #pragma unroll
    for (int m = 0; m < 4; ++m) {
        #pragma unroll
        for (int j = 0; j < 4; ++j) {
            float v = rs[m][j];
            v += __shfl_xor(v, 1, 64);
            v += __shfl_xor(v, 2, 64);
            v += __shfl_xor(v, 4, 64);
            v += __shfl_xor(v, 8, 64);
            rs[m][j] = v;   // row-sum over this wave's 64 cols
        }
    }
    if (l15 == 0) {
        #pragma unroll
        for (int m = 0; m < 4; ++m)
            #pragma unroll
            for (int j = 0; j < 4; ++j)
                atomicAdd(&lds_rs[wr * 64 + m * 16 + kg * 4 + j], rs[m][j]);
    }
    __syncthreads();
    if (tid < BM) atomicAdd(&rowsum[row0 + tid], lds_rs[tid]);
}

// ---- label-column cosines: one wave per row (tiled workspace reads) ----
__global__ void label_dot(const unsigned short* __restrict__ fbT,
                          const unsigned short* __restrict__ wbT,
                          const int* __restrict__ labels,
                          float* __restrict__ coslab) {
    const int lane = threadIdx.x & 63;
    const int row  = blockIdx.x * 4 + (threadIdx.x >> 6);
    if (row >= NROWS) return;
    const int lab = labels[row];
    const size_t fo = (size_t)(row >> 7) * RB_U16 + (lane >> 2) * 4096
                    + (lane & 3) * 1024 + (row & 127) * 8;
    const size_t wo = (size_t)(lab >> 7) * RB_U16 + (lane >> 2) * 4096
                    + (lane & 3) * 1024 + (lab & 127) * 8;
    u16x8 a = *(const u16x8*)(fbT + fo);
    u16x8 b = *(const u16x8*)(wbT + wo);
    float s = 0.f;
    #pragma unroll
    for (int i = 0; i < 8; ++i) s = fmaf(bf2f(a[i]), bf2f(b[i]), s);
    #pragma unroll
    for (int m = 1; m < 64; m <<= 1) s += __shfl_xor(s, m, 64);
    if (lane == 0) coslab[row] = s;
}

// ---- finalize: margin math + logsumexp + mean NLL ----
__global__ void finalize(const float* __restrict__ rowsum,
                         const float* __restrict__ coslab,
                         float* __restrict__ out) {
    const float COS_M   =  0.87758256189f;  // cos(0.5)
    const float SIN_M   =  0.47942553860f;  // sin(0.5)
    const float MIN_COS = -0.87758256189f;  // cos(pi - 0.5)
    __shared__ float red[256];
    const int tid = threadIdx.x;
    float acc = 0.f;
    for (int r = tid; r < NROWS; r += 256) {
        float c = fminf(fmaxf(coslab[r], -1.f), 1.f);
        float sn = sqrtf(1.f - c * c + 1e-5f);
        float cm = c * COS_M - sn * SIN_M;
        float target = (c > MIN_COS) ? cm : (c - sn * 0.5f);
        float adj = rowsum[r] - fexp64(c) + fexp64(target);
        acc += 64.f + logf(adj) - 64.f * target;
    }
    red[tid] = acc;
    __syncthreads();
    for (int s = 128; s > 0; s >>= 1) {
        if (tid < s) red[tid] += red[tid + s];
        __syncthreads();
    }
    if (tid == 0) out[0] = red[0] / (float)NROWS;
}

extern "C" void kernel_launch(void* const* d_in, const int* in_sizes, int n_in,
                              void* d_out, int out_size, void* d_ws, size_t ws_size,
                              hipStream_t stream) {
    const float* feats  = (const float*)d_in[0];   // [8,128,512]
    const float* w      = (const float*)d_in[1];   // [100000,512]
    const int*   labels = (const int*)d_in[2];     // [1024]
    float* out = (float*)d_out;

    char* ws = (char*)d_ws;
    unsigned short* wbT = (unsigned short*)ws;                               // C_PAD*512 bf16 tiled
    unsigned short* fbT = (unsigned short*)(ws + (size_t)C_PAD * KDIM * 2);  // 1024*512 bf16 tiled
    float* rowsum = (float*)(ws + (size_t)C_PAD * KDIM * 2
                                + (size_t)NROWS * KDIM * 2);                 // [1024]
    float* coslab = rowsum + NROWS;                                          // [1024]

    hipMemsetAsync(rowsum, 0, NROWS * sizeof(float), stream);
    norm_rows_tiled<<<C_PAD / 4, 256, 0, stream>>>(w, wbT, NUM_CLASSES);
    norm_rows_tiled<<<NROWS / 4, 256, 0, stream>>>(feats, fbT, NROWS);
    arcface_gemm<<<(C_PAD / BN) * (NROWS / BM), 256, 0, stream>>>(fbT, wbT, rowsum);
    label_dot<<<NROWS / 4, 256, 0, stream>>>(fbT, wbT, labels, coslab);
    finalize<<<1, 256, 0, stream>>>(rowsum, coslab, out);
}

// Round 6
// 422.683 us; speedup vs baseline: 1.1379x; 1.1010x over previous
//
#include <hip/hip_runtime.h>
#include <hip/hip_bf16.h>
#include <stdint.h>

#define NUM_CLASSES 100000
#define C_PAD       100096   // 782 * 128
#define NCHUNK      391      // 100096 / 256 column chunks
#define NROWS       1024
#define KDIM        512
#define NKT         16       // K-tiles of 32
#define TILE_BYTES  8192     // 128 rows * 64 B (workspace tiling granule)
#define RB_BYTES    (NKT * TILE_BYTES)   // 131072 B per 128-row block
#define RB_U16      (RB_BYTES / 2)       // 65536

#define L2E64 92.3324826f    // 64 * log2(e)

typedef __bf16 bf16x8 __attribute__((ext_vector_type(8)));
typedef float  f32x4  __attribute__((ext_vector_type(4)));
typedef unsigned short u16x8 __attribute__((ext_vector_type(8)));

__device__ __forceinline__ unsigned short f2bf(float x) {
    unsigned int u = __float_as_uint(x);
    u = u + 0x7fffu + ((u >> 16) & 1u);   // RNE
    return (unsigned short)(u >> 16);
}
__device__ __forceinline__ float bf2f(unsigned short x) {
    return __uint_as_float(((unsigned int)x) << 16);
}
// exp(64*c - 64) via native exp2 — identical in gemm and finalize
__device__ __forceinline__ float fexp64(float c) {
    return exp2f(fmaf(c, L2E64, -L2E64));
}
__device__ __forceinline__ void gload_lds16(const void* g, void* l) {
    __builtin_amdgcn_global_load_lds(
        (const __attribute__((address_space(1))) unsigned int*)g,
        (__attribute__((address_space(3))) unsigned int*)l,
        16, 0, 0);
}

// Tiled workspace layout: row r, K-chunk (kt,kg) [8 bf16 = 16 B] lives at
//   u16 offset: (r>>7)*RB_U16 + kt*4096 + kg*1024 + (r&127)*8
// A wave MFMA fragment (16 rows x 8 K) is 16 contiguous bytes per lane ->
// B fragments load global->VGPR directly; A stages linearly via global_load_lds.

// ---- normalize rows of [rows x 512] f32 -> bf16 tiled, LDS-bounced writes ----
__global__ void norm_rows_tiled(const float* __restrict__ in,
                                unsigned short* __restrict__ out,
                                int rows_valid) {
    __shared__ __align__(16) unsigned short stg[4 * 64 * 8];  // 4 KB
    const int tid  = threadIdx.x;
    const int lane = tid & 63;
    const int wv   = tid >> 6;
    const int row  = blockIdx.x * 4 + wv;

    u16x8 o;
    #pragma unroll
    for (int i = 0; i < 8; ++i) o[i] = 0;
    if (row < rows_valid) {
        const float4* p = (const float4*)(in + (size_t)row * KDIM + lane * 8);
        float4 a = p[0], b = p[1];
        float ss = a.x*a.x + a.y*a.y + a.z*a.z + a.w*a.w
                 + b.x*b.x + b.y*b.y + b.z*b.z + b.w*b.w;
        #pragma unroll
        for (int m = 1; m < 64; m <<= 1) ss += __shfl_xor(ss, m, 64);
        float scale = 1.0f / fmaxf(sqrtf(ss), 1e-12f);
        float v[8] = {a.x, a.y, a.z, a.w, b.x, b.y, b.z, b.w};
        #pragma unroll
        for (int i = 0; i < 8; ++i) o[i] = f2bf(v[i] * scale);
    }
    *(u16x8*)&stg[(wv * 64 + lane) * 8] = o;
    __syncthreads();

    // write phase: thread t -> chunk c = t>>2, row-in-4 = t&3 (64B segments)
    const int c    = tid >> 2;
    const int r4   = tid & 3;
    const int rowg = blockIdx.x * 4 + r4;
    u16x8 v = *(const u16x8*)&stg[(r4 * 64 + c) * 8];
    const size_t dst = (size_t)(rowg >> 7) * RB_U16
                     + (c >> 2) * 4096 + (c & 3) * 1024 + (rowg & 127) * 8;
    *(u16x8*)(out + dst) = v;
}

// ---- main GEMM: A resident in LDS, B global->reg, barrier-free main loop ----
__global__ __launch_bounds__(256, 2) void arcface_gemm(
        const unsigned short* __restrict__ fbT,  // tiled [8 RB][16 kt][4 kg][128][8]
        const unsigned short* __restrict__ wbT,  // tiled [782 RB][...]
        float* __restrict__ rowsum) {            // [1024] f32, pre-zeroed
    __shared__ __align__(16) unsigned short ldsA[32768];  // 64 KB: [kt][kg][64 rows][8]

    const int tid  = threadIdx.x;
    const int lane = tid & 63;
    const int wid  = tid >> 6;    // wave 0..3 -> 64-col strip within chunk
    const int l15  = lane & 15;
    const int kg   = lane >> 4;

    // grid 512 = 16 mblk x 32 col-groups; chunked XCD swizzle, mblk-fastest:
    // the 16 M-blocks sharing a B strip are co-resident on ONE XCD.
    const int swz  = (blockIdx.x & 7) * 64 + (blockIdx.x >> 3);
    const int mblk = swz & 15;    // 64-row block of A
    const int g    = swz >> 4;    // column group (0..31)
    const int row0 = mblk * 64;

    const char* aBase = (const char*)fbT + (size_t)(mblk >> 1) * RB_BYTES;
    const int   roffB = (mblk & 1) * (64 * 16);   // row-half byte offset in RB
    const char* wbB   = (const char*)wbT;

    // ---- stage A-tile (64 rows x 512 K = 64 KB) once, linearly ----
    #pragma unroll
    for (int i = 0; i < 16; ++i) {
        const int c  = i * 256 + tid;        // 16B-chunk id 0..4095
        const int kt = c >> 8;
        const int kr = c & 255;              // kg = kr>>6, row = kr&63
        gload_lds16(aBase + kt * 8192 + (kr >> 6) * 2048 + roffB + (kr & 63) * 16,
                    (char*)ldsA + c * 16);
    }
    __syncthreads();   // drains global_load_lds; the ONLY barrier

    float rsAcc[4][4];
    #pragma unroll
    for (int m = 0; m < 4; ++m)
        #pragma unroll
        for (int j = 0; j < 4; ++j) rsAcc[m][j] = 0.f;

    for (int jc = 0; jc < 13; ++jc) {
        const int cchunk = g + 32 * jc;
        if (cchunk >= NCHUNK) break;
        const int col0 = cchunk * 256 + wid * 64;
        const char* bBase = wbB + (size_t)(col0 >> 7) * RB_BYTES
                                + (col0 & 127) * 16;

        f32x4 acc[4][4];
        #pragma unroll
        for (int m = 0; m < 4; ++m)
            #pragma unroll
            for (int n = 0; n < 4; ++n)
                #pragma unroll
                for (int j = 0; j < 4; ++j) acc[m][n][j] = 0.f;

        for (int kt = 0; kt < NKT; ++kt) {
            bf16x8 bfr[4], af[4];
            #pragma unroll
            for (int n = 0; n < 4; ++n)
                bfr[n] = *(const bf16x8*)(bBase + kt * 8192 + kg * 2048
                                          + (n * 16 + l15) * 16);
            #pragma unroll
            for (int m = 0; m < 4; ++m)
                af[m] = *(const bf16x8*)((const char*)ldsA + kt * 4096 + kg * 1024
                                         + (m * 16 + l15) * 16);
            #pragma unroll
            for (int m = 0; m < 4; ++m)
                #pragma unroll
                for (int n = 0; n < 4; ++n)
                    acc[m][n] = __builtin_amdgcn_mfma_f32_16x16x32_bf16(
                                    af[m], bfr[n], acc[m][n], 0, 0, 0);
        }

        // fold this chunk into register exp-sums (pad cols ~ exp(-64): no mask)
        #pragma unroll
        for (int m = 0; m < 4; ++m)
            #pragma unroll
            for (int n = 0; n < 4; ++n)
                #pragma unroll
                for (int j = 0; j < 4; ++j) {
                    float c = acc[m][n][j];
                    c = fminf(fmaxf(c, -1.f), 1.f);
                    rsAcc[m][j] += fexp64(c);
                }
    }

    // final reduce over the 16 l15 lanes, one atomic per row per block
    #pragma unroll
    for (int m = 0; m < 4; ++m) {
        #pragma unroll
        for (int j = 0; j < 4; ++j) {
            float v = rsAcc[m][j];
            v += __shfl_xor(v, 1, 64);
            v += __shfl_xor(v, 2, 64);
            v += __shfl_xor(v, 4, 64);
            v += __shfl_xor(v, 8, 64);
            if (l15 == 0)
                atomicAdd(&rowsum[row0 + m * 16 + kg * 4 + j], v);
        }
    }
}

// ---- label-column cosines: one wave per row (tiled workspace reads) ----
__global__ void label_dot(const unsigned short* __restrict__ fbT,
                          const unsigned short* __restrict__ wbT,
                          const int* __restrict__ labels,
                          float* __restrict__ coslab) {
    const int lane = threadIdx.x & 63;
    const int row  = blockIdx.x * 4 + (threadIdx.x >> 6);
    if (row >= NROWS) return;
    const int lab = labels[row];
    const size_t fo = (size_t)(row >> 7) * RB_U16 + (lane >> 2) * 4096
                    + (lane & 3) * 1024 + (row & 127) * 8;
    const size_t wo = (size_t)(lab >> 7) * RB_U16 + (lane >> 2) * 4096
                    + (lane & 3) * 1024 + (lab & 127) * 8;
    u16x8 a = *(const u16x8*)(fbT + fo);
    u16x8 b = *(const u16x8*)(wbT + wo);
    float s = 0.f;
    #pragma unroll
    for (int i = 0; i < 8; ++i) s = fmaf(bf2f(a[i]), bf2f(b[i]), s);
    #pragma unroll
    for (int m = 1; m < 64; m <<= 1) s += __shfl_xor(s, m, 64);
    if (lane == 0) coslab[row] = s;
}

// ---- finalize: margin math + logsumexp + mean NLL ----
__global__ void finalize(const float* __restrict__ rowsum,
                         const float* __restrict__ coslab,
                         float* __restrict__ out) {
    const float COS_M   =  0.87758256189f;  // cos(0.5)
    const float SIN_M   =  0.47942553860f;  // sin(0.5)
    const float MIN_COS = -0.87758256189f;  // cos(pi - 0.5)
    __shared__ float red[256];
    const int tid = threadIdx.x;
    float acc = 0.f;
    for (int r = tid; r < NROWS; r += 256) {
        float c = fminf(fmaxf(coslab[r], -1.f), 1.f);
        float sn = sqrtf(1.f - c * c + 1e-5f);
        float cm = c * COS_M - sn * SIN_M;
        float target = (c > MIN_COS) ? cm : (c - sn * 0.5f);
        float adj = rowsum[r] - fexp64(c) + fexp64(target);
        acc += 64.f + logf(adj) - 64.f * target;
    }
    red[tid] = acc;
    __syncthreads();
    for (int s = 128; s > 0; s >>= 1) {
        if (tid < s) red[tid] += red[tid + s];
        __syncthreads();
    }
    if (tid == 0) out[0] = red[0] / (float)NROWS;
}

extern "C" void kernel_launch(void* const* d_in, const int* in_sizes, int n_in,
                              void* d_out, int out_size, void* d_ws, size_t ws_size,
                              hipStream_t stream) {
    const float* feats  = (const float*)d_in[0];   // [8,128,512]
    const float* w      = (const float*)d_in[1];   // [100000,512]
    const int*   labels = (const int*)d_in[2];     // [1024]
    float* out = (float*)d_out;

    char* ws = (char*)d_ws;
    unsigned short* wbT = (unsigned short*)ws;                               // C_PAD*512 bf16 tiled
    unsigned short* fbT = (unsigned short*)(ws + (size_t)C_PAD * KDIM * 2);  // 1024*512 bf16 tiled
    float* rowsum = (float*)(ws + (size_t)C_PAD * KDIM * 2
                                + (size_t)NROWS * KDIM * 2);                 // [1024]
    float* coslab = rowsum + NROWS;                                          // [1024]

    hipMemsetAsync(rowsum, 0, NROWS * sizeof(float), stream);
    norm_rows_tiled<<<C_PAD / 4, 256, 0, stream>>>(w, wbT, NUM_CLASSES);
    norm_rows_tiled<<<NROWS / 4, 256, 0, stream>>>(feats, fbT, NROWS);
    arcface_gemm<<<512, 256, 0, stream>>>(fbT, wbT, rowsum);
    label_dot<<<NROWS / 4, 256, 0, stream>>>(fbT, wbT, labels, coslab);
    finalize<<<1, 256, 0, stream>>>(rowsum, coslab, out);
}